// Round 9
// baseline (238.400 us; speedup 1.0000x reference)
//
#include <hip/hip_runtime.h>

#define NEMB 512
#define EMB 64
#define BSTR 262144          // 64*4096
#define DECAYF 0.99f
#define OMDF 0.01f
#define EPSF 1e-5f
#define GAP_T 4e-4f          // FULL split-bf16 err <~5e-5 -> 8x margin; queue ~tens
#define QCAP 32768           // flagged-token queue capacity

typedef __attribute__((ext_vector_type(8))) short bf16x8;
typedef __attribute__((ext_vector_type(4))) float f32x4;

__device__ __forceinline__ unsigned short f2bf(float f) {
    unsigned u = __float_as_uint(f);
    return (unsigned short)((u + 0x7FFFu + ((u >> 16) & 1u)) >> 16);   // RNE
}
__device__ __forceinline__ float bf2f(unsigned short h) {
    return __uint_as_float(((unsigned)h) << 16);
}

// global->LDS DMA, 16B/lane. LDS dest = wave-uniform base + lane*16 (HW rule);
// global src is per-lane (swizzles applied on the SOURCE address).
__device__ __forceinline__ void gl2lds16(const void* g, void* l) {
    __builtin_amdgcn_global_load_lds(
        (const __attribute__((address_space(1))) unsigned int*)g,
        (__attribute__((address_space(3))) unsigned int*)l, 16, 0, 0);
}

// 9 blocks x 512 threads.
__global__ void prep_kernel(const float* __restrict__ w,
                            unsigned short* __restrict__ wh, unsigned short* __restrict__ wl,
                            float* __restrict__ wsq,
                            float* __restrict__ cnt_ws, unsigned* __restrict__ gcnt) {
    int j = threadIdx.x;
    if (blockIdx.x < 8) {
        int d0 = blockIdx.x << 3;
        bf16x8 hb, lb;
#pragma unroll
        for (int i = 0; i < 8; ++i) {
            float v = w[(d0 + i) * NEMB + j];
            unsigned short h = f2bf(v);
            hb[i] = (short)h;
            lb[i] = (short)f2bf(v - bf2f(h));
        }
        *(bf16x8*)(wh + j * EMB + d0) = hb;
        *(bf16x8*)(wl + j * EMB + d0) = lb;
    } else {
        float s = 0.f;
#pragma unroll
        for (int d = 0; d < EMB; ++d) { float v = w[d * NEMB + j]; s = fmaf(v, v, s); }
        wsq[j] = s;
        cnt_ws[j] = 0.f;
        if (j == 0) *gcnt = 0u;
    }
}

#define UPD(S1, J1, S2, J2, s_, j_) do { \
    if (s_ < S1 || (s_ == S1 && j_ < J1)) { S2 = S1; J2 = J1; S1 = s_; J1 = j_; } \
    else if (s_ < S2 || (s_ == S2 && j_ < J2)) { S2 = s_; J2 = j_; } } while (0)

// r9: 1024 blocks x 512 threads x 128 tokens. r8's 512-block grid capped residency
// at 2 blocks/CU regardless of the 34.8KB LDS (grid/CU = 2!) -> occupancy stayed 37%.
// 1024 blocks -> 4 blocks/CU; launch_bounds(512,8) pins VGPR<=64 (per-wave state
// halved: 1 token-group/wave). FULL split-bf16 (+lo*lo term, 8 MFMA/iter) cuts
// distance error to ~5e-5, letting GAP_T drop 0.006->4e-4: the refine queue
// (each flagged token re-reads all 128KB of w from L2!) shrinks ~100x.
__global__ __launch_bounds__(512, 8) void vq_main(
    const float* __restrict__ x,
    const unsigned short* __restrict__ wh, const unsigned short* __restrict__ wl,
    const float* __restrict__ wsq,
    float* __restrict__ out_arg, unsigned* __restrict__ gcnt, int* __restrict__ queue)
{
    __shared__ __align__(16) unsigned char ubuf[32768];   // union: x tile | cb quarter
    __shared__ float wsq_s[NEMB];

    float* xt = (float*)ubuf;                        // [64][128] f32 = 32KB
    unsigned short* whq = (unsigned short*)ubuf;     // [128][64] bf16-hi (swizzled)
    unsigned short* wlq = whq + 8192;                // [128][64] bf16-lo (swizzled)

    const int tid = threadIdx.x;
    const int blk = blockIdx.x;          // 1024
    const int b    = blk >> 5;
    const int hgrp = blk & 31;
    const int t0 = b * 4096 + hgrp * 128;
    const float* xbase = x + b * BSTR + hgrp * 128;

    const int lane = tid & 63;
    const int wave = tid >> 6;

    // ---- stage x tile: 32 chunks of 1KB (2 rows of 128 f32 each) ----
#pragma unroll
    for (int it = 0; it < 4; ++it) {
        int ch = wave + (it << 3);
        int d0 = ch << 1;
        gl2lds16(xbase + (d0 + (lane >> 5)) * 4096 + ((lane & 31) << 2),
                 xt + d0 * 128);
    }
    wsq_s[tid] = wsq[tid];
    __syncthreads();                     // xt + wsq ready

    const int l15  = lane & 15;
    const int quad = lane >> 4;
    const int wbase = wave << 4;         // 16 tokens per wave

    // ---- A fragments (hi/lo split) + fused ||x||^2 ----
    bf16x8 ah[2], al[2];
    float xq[4];
    {
        int m = wbase + l15;
        float sq = 0.f;
#pragma unroll
        for (int ks = 0; ks < 2; ++ks) {
            int k0 = (ks << 5) + (quad << 3);
            bf16x8 hh, ll;
#pragma unroll
            for (int i = 0; i < 8; ++i) {
                float v = xt[(k0 + i) * 128 + m];
                sq = fmaf(v, v, sq);
                unsigned short h = f2bf(v);
                hh[i] = (short)h;
                ll[i] = (short)f2bf(v - bf2f(h));
            }
            ah[ks] = hh; al[ks] = ll;
        }
        sq += __shfl_xor(sq, 16, 64);    // quads hold disjoint 16-dim partials
        sq += __shfl_xor(sq, 32, 64);
#pragma unroll
        for (int r = 0; r < 4; ++r)
            xq[r] = __shfl(sq, (quad << 2) + r, 64);
    }
    __syncthreads();                     // xt dead; ubuf free for codebook

    float v1[4], v2[4];
    int   j1[4];
#pragma unroll
    for (int r = 0; r < 4; ++r) { v1[r] = 3.4e38f; v2[r] = 3.4e38f; j1[r] = 0; }

    const int m7 = l15 & 7;
    const int s0off = ((quad ^ m7) << 3);
    const int s1off = (((4 | quad) ^ m7) << 3);

    // ---- stage codebook quarter 0 (codes 0..127, hi+lo = 32KB) ----
#pragma unroll
    for (int it = 0; it < 4; ++it) {
        int g0 = (wave << 6) + (it << 9);        // granule base, uniform per wave
        int arr = g0 >> 10;                      // 0: hi, 1: lo (uniform)
        int win0 = g0 & 1023;
        int win = win0 + lane;
        int row = win >> 3, slot = win & 7;
        const unsigned short* src =
            (arr ? wl : wh) + row * EMB + ((slot ^ (row & 7)) << 3);
        gl2lds16(src, (arr ? wlq : whq) + (win0 << 3));
    }
    __syncthreads();                     // Q0 ready

    for (int q = 0; q < 4; ++q) {
        const int nbase = q << 7;
#pragma unroll 2
        for (int it = 0; it < 8; ++it) {
            const int ib = ((it << 4) + l15) << 6;    // row*64 shorts, row 0..127
            bf16x8 b0 = *(const bf16x8*)(whq + ib + s0off);
            bf16x8 b1 = *(const bf16x8*)(whq + ib + s1off);
            bf16x8 b2 = *(const bf16x8*)(wlq + ib + s0off);
            bf16x8 b3 = *(const bf16x8*)(wlq + ib + s1off);
            const int n = nbase + (it << 4) + l15;
            float wq = wsq_s[n];

            // FULL split product: hi*hi + hi*lo + lo*hi + lo*lo (8 MFMA)
            f32x4 acc = (f32x4){0.f, 0.f, 0.f, 0.f};
            acc = __builtin_amdgcn_mfma_f32_16x16x32_bf16(ah[0], b0, acc, 0, 0, 0);
            acc = __builtin_amdgcn_mfma_f32_16x16x32_bf16(ah[1], b1, acc, 0, 0, 0);
            acc = __builtin_amdgcn_mfma_f32_16x16x32_bf16(ah[0], b2, acc, 0, 0, 0);
            acc = __builtin_amdgcn_mfma_f32_16x16x32_bf16(ah[1], b3, acc, 0, 0, 0);
            acc = __builtin_amdgcn_mfma_f32_16x16x32_bf16(al[0], b0, acc, 0, 0, 0);
            acc = __builtin_amdgcn_mfma_f32_16x16x32_bf16(al[1], b1, acc, 0, 0, 0);
            acc = __builtin_amdgcn_mfma_f32_16x16x32_bf16(al[0], b2, acc, 0, 0, 0);
            acc = __builtin_amdgcn_mfma_f32_16x16x32_bf16(al[1], b3, acc, 0, 0, 0);

#pragma unroll
            for (int r = 0; r < 4; ++r) {
                float s0 = fmaf(-2.f, acc[r], xq[r] + wq);
                bool p0 = s0 < v1[r];
                float mx0 = fmaxf(s0, v1[r]);
                v1[r] = fminf(s0, v1[r]);
                v2[r] = fminf(v2[r], mx0);
                j1[r] = p0 ? n : j1[r];
            }
        }
        if (q < 3) {
            __syncthreads();             // quarter q dead
#pragma unroll
            for (int it = 0; it < 4; ++it) {
                int g0 = (wave << 6) + (it << 9);
                int arr = g0 >> 10;
                int win0 = g0 & 1023;
                int win = win0 + lane;
                int row = win >> 3, slot = win & 7;
                const unsigned short* src =
                    (arr ? wl : wh) + (((q + 1) << 7) + row) * EMB + ((slot ^ (row & 7)) << 3);
                gl2lds16(src, (arr ? wlq : whq) + (win0 << 3));
            }
            __syncthreads();             // quarter q+1 ready
        }
    }

    // butterfly merge (v1,j1,v2) across the 16 lanes sharing each token
#pragma unroll
    for (int r = 0; r < 4; ++r) {
        float a1 = v1[r], a2 = v2[r];
        int   aj = j1[r];
#pragma unroll
        for (int msk = 1; msk < 16; msk <<= 1) {
            float o1 = __shfl_xor(a1, msk, 64);
            int   oj = __shfl_xor(aj, msk, 64);
            float o2 = __shfl_xor(a2, msk, 64);
            bool take = (o1 < a1) || (o1 == a1 && oj < aj);
            float mx = fmaxf(a1, o1);
            a2 = fminf(fminf(a2, o2), mx);
            a1 = fminf(a1, o1);
            aj = take ? oj : aj;
        }
        v1[r] = a1; v2[r] = a2; j1[r] = aj;
    }

    if (l15 == 0) {
#pragma unroll
        for (int r = 0; r < 4; ++r) {
            int gt = t0 + wbase + (quad << 2) + r;
            out_arg[gt] = (float)j1[r];
            if (v2[r] - v1[r] < GAP_T) {
                unsigned idx = atomicAdd(gcnt, 1u);
                if (idx < QCAP) queue[idx] = gt;
            }
        }
    }
}

// Globally balanced exact refine (unchanged; now sees a ~100x smaller queue).
__global__ __launch_bounds__(256) void refine_kernel(
    const float* __restrict__ x, const float* __restrict__ w,
    const float* __restrict__ wsq, const unsigned* __restrict__ gcnt,
    const int* __restrict__ queue, float* __restrict__ out_arg)
{
    __shared__ float wsq_s[NEMB];
    const int tid = threadIdx.x;
    wsq_s[tid] = wsq[tid];
    wsq_s[tid + 256] = wsq[tid + 256];
    __syncthreads();

    unsigned nfu = *gcnt;
    const int nf = (int)(nfu < (unsigned)QCAP ? nfu : (unsigned)QCAP);
    const int lane = tid & 63;
    const int gw = (blockIdx.x << 2) + (tid >> 6);

    for (int i = gw; i < nf; i += 1024) {
        const int t = queue[i] & 131071;
        const int b = t >> 12, pos = t & 4095;
        float xd = x[b * BSTR + lane * 4096 + pos];
        float xqv = xd * xd;
#pragma unroll
        for (int mk = 1; mk < 64; mk <<= 1) xqv += __shfl_xor(xqv, mk, 64);

        float accv[8];
#pragma unroll
        for (int k = 0; k < 8; ++k) accv[k] = 0.f;
#pragma unroll 4
        for (int d = 0; d < EMB; ++d) {
            float4 wa = *(const float4*)(w + d * NEMB + (lane << 2));
            float4 wb = *(const float4*)(w + d * NEMB + 256 + (lane << 2));
            float xv = __shfl(xd, d, 64);
            accv[0] = fmaf(xv, wa.x, accv[0]);
            accv[1] = fmaf(xv, wa.y, accv[1]);
            accv[2] = fmaf(xv, wa.z, accv[2]);
            accv[3] = fmaf(xv, wa.w, accv[3]);
            accv[4] = fmaf(xv, wb.x, accv[4]);
            accv[5] = fmaf(xv, wb.y, accv[5]);
            accv[6] = fmaf(xv, wb.z, accv[6]);
            accv[7] = fmaf(xv, wb.w, accv[7]);
        }

        float S1 = 3.4e38f, S2 = 3.4e38f; int J1 = 0, J2 = 0;
#pragma unroll
        for (int k = 0; k < 8; ++k) {
            int j = (k < 4) ? ((lane << 2) + k) : (256 + (lane << 2) + k - 4);
            float s = (xqv - 2.f * accv[k]) + wsq_s[j];
            UPD(S1, J1, S2, J2, s, j);
        }
#pragma unroll
        for (int mk = 1; mk < 64; mk <<= 1) {
            float os1 = __shfl_xor(S1, mk, 64); int oj1 = __shfl_xor(J1, mk, 64);
            float os2 = __shfl_xor(S2, mk, 64); int oj2 = __shfl_xor(J2, mk, 64);
            UPD(S1, J1, S2, J2, os1, oj1);
            UPD(S1, J1, S2, J2, os2, oj2);
        }

        int jm = J1;
        if (S2 - S1 < 1e-3f) {
            float w1 = w[lane * NEMB + J1];
            float w2 = w[lane * NEMB + J2];
            double e1 = (double)w1 * (double)w1 - 2.0 * (double)xd * (double)w1;
            double e2 = (double)w2 * (double)w2 - 2.0 * (double)xd * (double)w2;
#pragma unroll
            for (int mk = 1; mk < 64; mk <<= 1) {
                e1 += __shfl_xor(e1, mk, 64);
                e2 += __shfl_xor(e2, mk, 64);
            }
            if (e2 < e1 || (e2 == e1 && J2 < J1)) jm = J2;
        }
        if (lane == 0) out_arg[t] = (float)jm;
    }
}

// es GEMM (r6-verified, unchanged): 512 blocks, 512 tokens/block, bf16-HI only.
__global__ __launch_bounds__(512, 4) void es_kernel(
    const float* __restrict__ x, const float* __restrict__ arg,
    float* __restrict__ es_p, float* __restrict__ cnt_ws)
{
    __shared__ unsigned short xh[16384];   // [64][256] bf16-hi, swizzled
    __shared__ int args_s[256];
    __shared__ float cacc[NEMB];

    const int tid = threadIdx.x;
    const int blk = blockIdx.x;          // 512
    const int flavor = blk & 1;          // j range [flavor*256, +256)
    const int chunk  = blk >> 1;         // 0..255, 512 tokens
    const int b = chunk >> 3;
    const int tpos0 = (chunk & 7) << 9;

    cacc[tid] = 0.f;

    const int lane = tid & 63;
    const int wave = tid >> 6;
    const int l15  = lane & 15;
    const int quad = lane >> 4;
    const int jb   = wave << 5;

    f32x4 acc[4][2];
#pragma unroll
    for (int m = 0; m < 4; ++m)
#pragma unroll
        for (int nc = 0; nc < 2; ++nc) acc[m][nc] = (f32x4){0.f, 0.f, 0.f, 0.f};

    for (int st = 0; st < 2; ++st) {
        const int tpos = tpos0 + (st << 8);
#pragma unroll
        for (int it = 0; it < 8; ++it) {
            int idx = tid + (it << 9);
            int d = idx >> 6, q = idx & 63;
            float4 g = *(const float4*)(x + b * BSTR + d * 4096 + tpos + (q << 2));
            int c = q >> 1, half = q & 1;
            int off = d * 256 + ((c ^ (d & 7)) << 3) + (half << 2);
            ushort4 hv = {f2bf(g.x), f2bf(g.y), f2bf(g.z), f2bf(g.w)};
            *(ushort4*)(xh + off) = hv;
        }
        if (tid < 256) args_s[tid] = ((int)arg[b * 4096 + tpos + tid]) & 511;
        __syncthreads();

        if (flavor == 0 && tid < 256) atomicAdd(&cacc[args_s[tid]], 1.f);

#pragma unroll
        for (int kk = 0; kk < 8; ++kk) {
            bf16x8 a_[4];
#pragma unroll
            for (int m = 0; m < 4; ++m) {
                int d = (m << 4) + l15;
                int coff = ((((kk << 2) + quad) ^ (d & 7)) << 3);
                a_[m] = *(const bf16x8*)(xh + d * 256 + coff);
            }
            int argv[8];
            const int kb = (kk << 5) + (quad << 3);
#pragma unroll
            for (int i = 0; i < 8; ++i) argv[i] = args_s[kb + i];
#pragma unroll
            for (int nc = 0; nc < 2; ++nc) {
                const int jg = (flavor << 8) + jb + (nc << 4) + l15;   // GLOBAL code id
                bf16x8 bf;
#pragma unroll
                for (int i = 0; i < 8; ++i) bf[i] = (argv[i] == jg) ? (short)0x3F80 : (short)0;
#pragma unroll
                for (int m = 0; m < 4; ++m)
                    acc[m][nc] = __builtin_amdgcn_mfma_f32_16x16x32_bf16(a_[m], bf, acc[m][nc], 0, 0, 0);
            }
        }
        __syncthreads();
    }

    // ---- flush deterministic partial: es_p[blk][d][jl] ----
    float* ep = es_p + blk * 16384;
#pragma unroll
    for (int m = 0; m < 4; ++m)
#pragma unroll
        for (int nc = 0; nc < 2; ++nc) {
            const int jl = jb + (nc << 4) + l15;
#pragma unroll
            for (int r = 0; r < 4; ++r) {
                const int d = (m << 4) + (quad << 2) + r;
                ep[d * 256 + jl] = acc[m][nc][r];
            }
        }
    if (flavor == 0) {
        float v = cacc[tid];
        if (v != 0.f) atomicAdd(&cnt_ws[tid], v);
    }
}

// fused finalize + es partial reduction: 128 blocks (64 d x 2 j-halves) x 256 thr.
__global__ __launch_bounds__(256) void finalize_kernel(
    const float* __restrict__ cs_in, const float* __restrict__ avg_in,
    const float* __restrict__ cnt_ws, const float* __restrict__ es_p,
    float* __restrict__ out_w, float* __restrict__ out_ncs,
    float* __restrict__ out_avg) {
    __shared__ float red[256];
    const int tid = threadIdx.x;
    const int d  = blockIdx.x >> 1;
    const int jh = blockIdx.x & 1;

    float c0 = cnt_ws[tid], c1 = cnt_ws[tid + 256];
    float ncs0 = DECAYF * cs_in[tid] + OMDF * ((c0 == 0.f) ? 1.f : c0);
    float ncs1 = DECAYF * cs_in[tid + 256] + OMDF * ((c1 == 0.f) ? 1.f : c1);
    red[tid] = ncs0 + ncs1;
    __syncthreads();
    for (int s = 128; s > 0; s >>= 1) {
        if (tid < s) red[tid] += red[tid + s];
        __syncthreads();
    }
    const float n = red[0];

    const float* ep = es_p + jh * 16384 + d * 256 + tid;
    float s = 0.f;
#pragma unroll 16
    for (int c = 0; c < 256; ++c) s += ep[c * 32768];

    const float ncs = jh ? ncs1 : ncs0;
    const float csj = (ncs + EPSF) / (n + (float)NEMB * EPSF) * n;
    const int o = d * NEMB + (jh << 8) + tid;
    const float navg = DECAYF * avg_in[o] + OMDF * s;
    out_avg[o] = navg;
    out_w[o] = navg / csj;
    if (blockIdx.x == 0) { out_ncs[tid] = ncs0; out_ncs[tid + 256] = ncs1; }
}

// pure gather result write (unchanged). Runs LAST (out_result overlays es_p).
__global__ __launch_bounds__(512) void result_kernel(
    const float* __restrict__ w, const float* __restrict__ arg,
    float* __restrict__ out_result)
{
    __shared__ float wrow8[8 * 512];
    const int tid = threadIdx.x;
    const int grp = blockIdx.x >> 6;
    const int chunk = blockIdx.x & 63;
#pragma unroll
    for (int d = 0; d < 8; ++d)
        wrow8[(d << 9) + tid] = w[((grp << 3) + d) * NEMB + tid];
    __syncthreads();

    const int t = (chunk << 11) + (tid << 2);
    const int o = (t >> 12) * BSTR + (t & 4095);
    float4 a4 = *(const float4*)(arg + t);
    int j0 = ((int)a4.x) & 511, j1 = ((int)a4.y) & 511;
    int j2 = ((int)a4.z) & 511, j3 = ((int)a4.w) & 511;
#pragma unroll
    for (int d = 0; d < 8; ++d) {
        const int dg = (grp << 3) + d;
        float4 r4 = {wrow8[(d << 9) + j0], wrow8[(d << 9) + j1],
                     wrow8[(d << 9) + j2], wrow8[(d << 9) + j3]};
        *(float4*)(out_result + o + dg * 4096) = r4;
    }
}

extern "C" void kernel_launch(void* const* d_in, const int* in_sizes, int n_in,
                              void* d_out, int out_size, void* d_ws, size_t ws_size,
                              hipStream_t stream) {
    (void)in_sizes; (void)n_in; (void)out_size; (void)ws_size;
    const float* x   = (const float*)d_in[0];
    const float* w   = (const float*)d_in[1];
    const float* cs  = (const float*)d_in[2];
    const float* avg = (const float*)d_in[3];

    float* out = (float*)d_out;
    float* out_result = out;                 // 8388608 floats
    float* out_arg    = out + 8388608;       // 131072
    float* out_w      = out + 8519680;       // 32768
    float* out_ncs    = out + 8552448;       // 512
    float* out_avg    = out + 8552960;       // 32768
    float* es_p       = out;                 // 32MB scratch in out_result region;
                                             // consumed by finalize BEFORE result_kernel

    char* wsb = (char*)d_ws;
    unsigned short* wh = (unsigned short*)wsb;             // 65536 B
    unsigned short* wl = (unsigned short*)(wsb + 65536);   // 65536 B
    float* wsq      = (float*)(wsb + 131072);              // 2048 B
    float* cnt_ws   = (float*)(wsb + 133120);              // 2048 B
    unsigned* gcnt  = (unsigned*)(wsb + 135168);           // 4 B
    int* queue      = (int*)(wsb + 135232);                // 131072 B

    prep_kernel<<<9, 512, 0, stream>>>(w, wh, wl, wsq, cnt_ws, gcnt);
    vq_main<<<1024, 512, 0, stream>>>(x, wh, wl, wsq, out_arg, gcnt, queue);
    refine_kernel<<<256, 256, 0, stream>>>(x, w, wsq, gcnt, queue, out_arg);
    es_kernel<<<512, 512, 0, stream>>>(x, out_arg, es_p, cnt_ws);
    finalize_kernel<<<128, 256, 0, stream>>>(cs, avg, cnt_ws, es_p, out_w, out_ncs, out_avg);
    result_kernel<<<512, 512, 0, stream>>>(w, out_arg, out_result);
}

// Round 10
// 178.458 us; speedup vs baseline: 1.3359x; 1.3359x over previous
//
#include <hip/hip_runtime.h>

#define NEMB 512
#define EMB 64
#define BSTR 262144          // 64*4096
#define DECAYF 0.99f
#define OMDF 0.01f
#define EPSF 1e-5f
#define GAP_T 4e-4f          // FULL split-bf16 err <~5e-5 -> 8x margin; queue ~tens
#define QCAP 32768           // flagged-token queue capacity

typedef __attribute__((ext_vector_type(8))) short bf16x8;
typedef __attribute__((ext_vector_type(4))) float f32x4;

__device__ __forceinline__ unsigned short f2bf(float f) {
    unsigned u = __float_as_uint(f);
    return (unsigned short)((u + 0x7FFFu + ((u >> 16) & 1u)) >> 16);   // RNE
}
__device__ __forceinline__ float bf2f(unsigned short h) {
    return __uint_as_float(((unsigned)h) << 16);
}

// global->LDS DMA, 16B/lane. LDS dest = wave-uniform base + lane*16 (HW rule);
// global src is per-lane (swizzles applied on the SOURCE address).
__device__ __forceinline__ void gl2lds16(const void* g, void* l) {
    __builtin_amdgcn_global_load_lds(
        (const __attribute__((address_space(1))) unsigned int*)g,
        (__attribute__((address_space(3))) unsigned int*)l, 16, 0, 0);
}

// 9 blocks x 512 threads.
__global__ void prep_kernel(const float* __restrict__ w,
                            unsigned short* __restrict__ wh, unsigned short* __restrict__ wl,
                            float* __restrict__ wsq,
                            float* __restrict__ cnt_ws, unsigned* __restrict__ gcnt) {
    int j = threadIdx.x;
    if (blockIdx.x < 8) {
        int d0 = blockIdx.x << 3;
        bf16x8 hb, lb;
#pragma unroll
        for (int i = 0; i < 8; ++i) {
            float v = w[(d0 + i) * NEMB + j];
            unsigned short h = f2bf(v);
            hb[i] = (short)h;
            lb[i] = (short)f2bf(v - bf2f(h));
        }
        *(bf16x8*)(wh + j * EMB + d0) = hb;
        *(bf16x8*)(wl + j * EMB + d0) = lb;
    } else {
        float s = 0.f;
#pragma unroll
        for (int d = 0; d < EMB; ++d) { float v = w[d * NEMB + j]; s = fmaf(v, v, s); }
        wsq[j] = s;
        cnt_ws[j] = 0.f;
        if (j == 0) *gcnt = 0u;
    }
}

#define UPD(S1, J1, S2, J2, s_, j_) do { \
    if (s_ < S1 || (s_ == S1 && j_ < J1)) { S2 = S1; J2 = J1; S1 = s_; J1 = j_; } \
    else if (s_ < S2 || (s_ == S2 && j_ < J2)) { S2 = s_; J2 = j_; } } while (0)

// r10: identical to r9 EXCEPT __launch_bounds__(512,4). r9's (512,8) forced VGPR
// to 32 -> total spill (FETCH 17->101MB, WRITE 0.5->90MB, vq 46->109us despite 76%
// occupancy). (512,4) caps at 128; compiler's natural alloc (~50-64, r8 measured 64)
// fits the 8-wave/EU budget, so HW still co-schedules 4 blocks/CU (LDS 34.8KB x4
// < 160KB). NEVER set bounds tighter than the measured natural allocation.
__global__ __launch_bounds__(512, 4) void vq_main(
    const float* __restrict__ x,
    const unsigned short* __restrict__ wh, const unsigned short* __restrict__ wl,
    const float* __restrict__ wsq,
    float* __restrict__ out_arg, unsigned* __restrict__ gcnt, int* __restrict__ queue)
{
    __shared__ __align__(16) unsigned char ubuf[32768];   // union: x tile | cb quarter
    __shared__ float wsq_s[NEMB];

    float* xt = (float*)ubuf;                        // [64][128] f32 = 32KB
    unsigned short* whq = (unsigned short*)ubuf;     // [128][64] bf16-hi (swizzled)
    unsigned short* wlq = whq + 8192;                // [128][64] bf16-lo (swizzled)

    const int tid = threadIdx.x;
    const int blk = blockIdx.x;          // 1024
    const int b    = blk >> 5;
    const int hgrp = blk & 31;
    const int t0 = b * 4096 + hgrp * 128;
    const float* xbase = x + b * BSTR + hgrp * 128;

    const int lane = tid & 63;
    const int wave = tid >> 6;

    // ---- stage x tile: 32 chunks of 1KB (2 rows of 128 f32 each) ----
#pragma unroll
    for (int it = 0; it < 4; ++it) {
        int ch = wave + (it << 3);
        int d0 = ch << 1;
        gl2lds16(xbase + (d0 + (lane >> 5)) * 4096 + ((lane & 31) << 2),
                 xt + d0 * 128);
    }
    wsq_s[tid] = wsq[tid];
    __syncthreads();                     // xt + wsq ready

    const int l15  = lane & 15;
    const int quad = lane >> 4;
    const int wbase = wave << 4;         // 16 tokens per wave

    // ---- A fragments (hi/lo split) + fused ||x||^2 ----
    bf16x8 ah[2], al[2];
    float xq[4];
    {
        int m = wbase + l15;
        float sq = 0.f;
#pragma unroll
        for (int ks = 0; ks < 2; ++ks) {
            int k0 = (ks << 5) + (quad << 3);
            bf16x8 hh, ll;
#pragma unroll
            for (int i = 0; i < 8; ++i) {
                float v = xt[(k0 + i) * 128 + m];
                sq = fmaf(v, v, sq);
                unsigned short h = f2bf(v);
                hh[i] = (short)h;
                ll[i] = (short)f2bf(v - bf2f(h));
            }
            ah[ks] = hh; al[ks] = ll;
        }
        sq += __shfl_xor(sq, 16, 64);    // quads hold disjoint 16-dim partials
        sq += __shfl_xor(sq, 32, 64);
#pragma unroll
        for (int r = 0; r < 4; ++r)
            xq[r] = __shfl(sq, (quad << 2) + r, 64);
    }
    __syncthreads();                     // xt dead; ubuf free for codebook

    float v1[4], v2[4];
    int   j1[4];
#pragma unroll
    for (int r = 0; r < 4; ++r) { v1[r] = 3.4e38f; v2[r] = 3.4e38f; j1[r] = 0; }

    const int m7 = l15 & 7;
    const int s0off = ((quad ^ m7) << 3);
    const int s1off = (((4 | quad) ^ m7) << 3);

    // ---- stage codebook quarter 0 (codes 0..127, hi+lo = 32KB) ----
#pragma unroll
    for (int it = 0; it < 4; ++it) {
        int g0 = (wave << 6) + (it << 9);        // granule base, uniform per wave
        int arr = g0 >> 10;                      // 0: hi, 1: lo (uniform)
        int win0 = g0 & 1023;
        int win = win0 + lane;
        int row = win >> 3, slot = win & 7;
        const unsigned short* src =
            (arr ? wl : wh) + row * EMB + ((slot ^ (row & 7)) << 3);
        gl2lds16(src, (arr ? wlq : whq) + (win0 << 3));
    }
    __syncthreads();                     // Q0 ready

    for (int q = 0; q < 4; ++q) {
        const int nbase = q << 7;
#pragma unroll 2
        for (int it = 0; it < 8; ++it) {
            const int ib = ((it << 4) + l15) << 6;    // row*64 shorts, row 0..127
            bf16x8 b0 = *(const bf16x8*)(whq + ib + s0off);
            bf16x8 b1 = *(const bf16x8*)(whq + ib + s1off);
            bf16x8 b2 = *(const bf16x8*)(wlq + ib + s0off);
            bf16x8 b3 = *(const bf16x8*)(wlq + ib + s1off);
            const int n = nbase + (it << 4) + l15;
            float wq = wsq_s[n];

            // FULL split product: hi*hi + hi*lo + lo*hi + lo*lo (8 MFMA)
            f32x4 acc = (f32x4){0.f, 0.f, 0.f, 0.f};
            acc = __builtin_amdgcn_mfma_f32_16x16x32_bf16(ah[0], b0, acc, 0, 0, 0);
            acc = __builtin_amdgcn_mfma_f32_16x16x32_bf16(ah[1], b1, acc, 0, 0, 0);
            acc = __builtin_amdgcn_mfma_f32_16x16x32_bf16(ah[0], b2, acc, 0, 0, 0);
            acc = __builtin_amdgcn_mfma_f32_16x16x32_bf16(ah[1], b3, acc, 0, 0, 0);
            acc = __builtin_amdgcn_mfma_f32_16x16x32_bf16(al[0], b0, acc, 0, 0, 0);
            acc = __builtin_amdgcn_mfma_f32_16x16x32_bf16(al[1], b1, acc, 0, 0, 0);
            acc = __builtin_amdgcn_mfma_f32_16x16x32_bf16(al[0], b2, acc, 0, 0, 0);
            acc = __builtin_amdgcn_mfma_f32_16x16x32_bf16(al[1], b3, acc, 0, 0, 0);

#pragma unroll
            for (int r = 0; r < 4; ++r) {
                float s0 = fmaf(-2.f, acc[r], xq[r] + wq);
                bool p0 = s0 < v1[r];
                float mx0 = fmaxf(s0, v1[r]);
                v1[r] = fminf(s0, v1[r]);
                v2[r] = fminf(v2[r], mx0);
                j1[r] = p0 ? n : j1[r];
            }
        }
        if (q < 3) {
            __syncthreads();             // quarter q dead
#pragma unroll
            for (int it = 0; it < 4; ++it) {
                int g0 = (wave << 6) + (it << 9);
                int arr = g0 >> 10;
                int win0 = g0 & 1023;
                int win = win0 + lane;
                int row = win >> 3, slot = win & 7;
                const unsigned short* src =
                    (arr ? wl : wh) + (((q + 1) << 7) + row) * EMB + ((slot ^ (row & 7)) << 3);
                gl2lds16(src, (arr ? wlq : whq) + (win0 << 3));
            }
            __syncthreads();             // quarter q+1 ready
        }
    }

    // butterfly merge (v1,j1,v2) across the 16 lanes sharing each token
#pragma unroll
    for (int r = 0; r < 4; ++r) {
        float a1 = v1[r], a2 = v2[r];
        int   aj = j1[r];
#pragma unroll
        for (int msk = 1; msk < 16; msk <<= 1) {
            float o1 = __shfl_xor(a1, msk, 64);
            int   oj = __shfl_xor(aj, msk, 64);
            float o2 = __shfl_xor(a2, msk, 64);
            bool take = (o1 < a1) || (o1 == a1 && oj < aj);
            float mx = fmaxf(a1, o1);
            a2 = fminf(fminf(a2, o2), mx);
            a1 = fminf(a1, o1);
            aj = take ? oj : aj;
        }
        v1[r] = a1; v2[r] = a2; j1[r] = aj;
    }

    if (l15 == 0) {
#pragma unroll
        for (int r = 0; r < 4; ++r) {
            int gt = t0 + wbase + (quad << 2) + r;
            out_arg[gt] = (float)j1[r];
            if (v2[r] - v1[r] < GAP_T) {
                unsigned idx = atomicAdd(gcnt, 1u);
                if (idx < QCAP) queue[idx] = gt;
            }
        }
    }
}

// Globally balanced exact refine (unchanged; sees a tiny queue at GAP_T=4e-4).
__global__ __launch_bounds__(256) void refine_kernel(
    const float* __restrict__ x, const float* __restrict__ w,
    const float* __restrict__ wsq, const unsigned* __restrict__ gcnt,
    const int* __restrict__ queue, float* __restrict__ out_arg)
{
    __shared__ float wsq_s[NEMB];
    const int tid = threadIdx.x;
    wsq_s[tid] = wsq[tid];
    wsq_s[tid + 256] = wsq[tid + 256];
    __syncthreads();

    unsigned nfu = *gcnt;
    const int nf = (int)(nfu < (unsigned)QCAP ? nfu : (unsigned)QCAP);
    const int lane = tid & 63;
    const int gw = (blockIdx.x << 2) + (tid >> 6);

    for (int i = gw; i < nf; i += 1024) {
        const int t = queue[i] & 131071;
        const int b = t >> 12, pos = t & 4095;
        float xd = x[b * BSTR + lane * 4096 + pos];
        float xqv = xd * xd;
#pragma unroll
        for (int mk = 1; mk < 64; mk <<= 1) xqv += __shfl_xor(xqv, mk, 64);

        float accv[8];
#pragma unroll
        for (int k = 0; k < 8; ++k) accv[k] = 0.f;
#pragma unroll 4
        for (int d = 0; d < EMB; ++d) {
            float4 wa = *(const float4*)(w + d * NEMB + (lane << 2));
            float4 wb = *(const float4*)(w + d * NEMB + 256 + (lane << 2));
            float xv = __shfl(xd, d, 64);
            accv[0] = fmaf(xv, wa.x, accv[0]);
            accv[1] = fmaf(xv, wa.y, accv[1]);
            accv[2] = fmaf(xv, wa.z, accv[2]);
            accv[3] = fmaf(xv, wa.w, accv[3]);
            accv[4] = fmaf(xv, wb.x, accv[4]);
            accv[5] = fmaf(xv, wb.y, accv[5]);
            accv[6] = fmaf(xv, wb.z, accv[6]);
            accv[7] = fmaf(xv, wb.w, accv[7]);
        }

        float S1 = 3.4e38f, S2 = 3.4e38f; int J1 = 0, J2 = 0;
#pragma unroll
        for (int k = 0; k < 8; ++k) {
            int j = (k < 4) ? ((lane << 2) + k) : (256 + (lane << 2) + k - 4);
            float s = (xqv - 2.f * accv[k]) + wsq_s[j];
            UPD(S1, J1, S2, J2, s, j);
        }
#pragma unroll
        for (int mk = 1; mk < 64; mk <<= 1) {
            float os1 = __shfl_xor(S1, mk, 64); int oj1 = __shfl_xor(J1, mk, 64);
            float os2 = __shfl_xor(S2, mk, 64); int oj2 = __shfl_xor(J2, mk, 64);
            UPD(S1, J1, S2, J2, os1, oj1);
            UPD(S1, J1, S2, J2, os2, oj2);
        }

        int jm = J1;
        if (S2 - S1 < 1e-3f) {
            float w1 = w[lane * NEMB + J1];
            float w2 = w[lane * NEMB + J2];
            double e1 = (double)w1 * (double)w1 - 2.0 * (double)xd * (double)w1;
            double e2 = (double)w2 * (double)w2 - 2.0 * (double)xd * (double)w2;
#pragma unroll
            for (int mk = 1; mk < 64; mk <<= 1) {
                e1 += __shfl_xor(e1, mk, 64);
                e2 += __shfl_xor(e2, mk, 64);
            }
            if (e2 < e1 || (e2 == e1 && J2 < J1)) jm = J2;
        }
        if (lane == 0) out_arg[t] = (float)jm;
    }
}

// es GEMM (r6-verified, unchanged): 512 blocks, 512 tokens/block, bf16-HI only.
__global__ __launch_bounds__(512, 4) void es_kernel(
    const float* __restrict__ x, const float* __restrict__ arg,
    float* __restrict__ es_p, float* __restrict__ cnt_ws)
{
    __shared__ unsigned short xh[16384];   // [64][256] bf16-hi, swizzled
    __shared__ int args_s[256];
    __shared__ float cacc[NEMB];

    const int tid = threadIdx.x;
    const int blk = blockIdx.x;          // 512
    const int flavor = blk & 1;          // j range [flavor*256, +256)
    const int chunk  = blk >> 1;         // 0..255, 512 tokens
    const int b = chunk >> 3;
    const int tpos0 = (chunk & 7) << 9;

    cacc[tid] = 0.f;

    const int lane = tid & 63;
    const int wave = tid >> 6;
    const int l15  = lane & 15;
    const int quad = lane >> 4;
    const int jb   = wave << 5;

    f32x4 acc[4][2];
#pragma unroll
    for (int m = 0; m < 4; ++m)
#pragma unroll
        for (int nc = 0; nc < 2; ++nc) acc[m][nc] = (f32x4){0.f, 0.f, 0.f, 0.f};

    for (int st = 0; st < 2; ++st) {
        const int tpos = tpos0 + (st << 8);
#pragma unroll
        for (int it = 0; it < 8; ++it) {
            int idx = tid + (it << 9);
            int d = idx >> 6, q = idx & 63;
            float4 g = *(const float4*)(x + b * BSTR + d * 4096 + tpos + (q << 2));
            int c = q >> 1, half = q & 1;
            int off = d * 256 + ((c ^ (d & 7)) << 3) + (half << 2);
            ushort4 hv = {f2bf(g.x), f2bf(g.y), f2bf(g.z), f2bf(g.w)};
            *(ushort4*)(xh + off) = hv;
        }
        if (tid < 256) args_s[tid] = ((int)arg[b * 4096 + tpos + tid]) & 511;
        __syncthreads();

        if (flavor == 0 && tid < 256) atomicAdd(&cacc[args_s[tid]], 1.f);

#pragma unroll
        for (int kk = 0; kk < 8; ++kk) {
            bf16x8 a_[4];
#pragma unroll
            for (int m = 0; m < 4; ++m) {
                int d = (m << 4) + l15;
                int coff = ((((kk << 2) + quad) ^ (d & 7)) << 3);
                a_[m] = *(const bf16x8*)(xh + d * 256 + coff);
            }
            int argv[8];
            const int kb = (kk << 5) + (quad << 3);
#pragma unroll
            for (int i = 0; i < 8; ++i) argv[i] = args_s[kb + i];
#pragma unroll
            for (int nc = 0; nc < 2; ++nc) {
                const int jg = (flavor << 8) + jb + (nc << 4) + l15;   // GLOBAL code id
                bf16x8 bf;
#pragma unroll
                for (int i = 0; i < 8; ++i) bf[i] = (argv[i] == jg) ? (short)0x3F80 : (short)0;
#pragma unroll
                for (int m = 0; m < 4; ++m)
                    acc[m][nc] = __builtin_amdgcn_mfma_f32_16x16x32_bf16(a_[m], bf, acc[m][nc], 0, 0, 0);
            }
        }
        __syncthreads();
    }

    // ---- flush deterministic partial: es_p[blk][d][jl] ----
    float* ep = es_p + blk * 16384;
#pragma unroll
    for (int m = 0; m < 4; ++m)
#pragma unroll
        for (int nc = 0; nc < 2; ++nc) {
            const int jl = jb + (nc << 4) + l15;
#pragma unroll
            for (int r = 0; r < 4; ++r) {
                const int d = (m << 4) + (quad << 2) + r;
                ep[d * 256 + jl] = acc[m][nc][r];
            }
        }
    if (flavor == 0) {
        float v = cacc[tid];
        if (v != 0.f) atomicAdd(&cnt_ws[tid], v);
    }
}

// fused finalize + es partial reduction: 128 blocks (64 d x 2 j-halves) x 256 thr.
__global__ __launch_bounds__(256) void finalize_kernel(
    const float* __restrict__ cs_in, const float* __restrict__ avg_in,
    const float* __restrict__ cnt_ws, const float* __restrict__ es_p,
    float* __restrict__ out_w, float* __restrict__ out_ncs,
    float* __restrict__ out_avg) {
    __shared__ float red[256];
    const int tid = threadIdx.x;
    const int d  = blockIdx.x >> 1;
    const int jh = blockIdx.x & 1;

    float c0 = cnt_ws[tid], c1 = cnt_ws[tid + 256];
    float ncs0 = DECAYF * cs_in[tid] + OMDF * ((c0 == 0.f) ? 1.f : c0);
    float ncs1 = DECAYF * cs_in[tid + 256] + OMDF * ((c1 == 0.f) ? 1.f : c1);
    red[tid] = ncs0 + ncs1;
    __syncthreads();
    for (int s = 128; s > 0; s >>= 1) {
        if (tid < s) red[tid] += red[tid + s];
        __syncthreads();
    }
    const float n = red[0];

    const float* ep = es_p + jh * 16384 + d * 256 + tid;
    float s = 0.f;
#pragma unroll 16
    for (int c = 0; c < 256; ++c) s += ep[c * 32768];

    const float ncs = jh ? ncs1 : ncs0;
    const float csj = (ncs + EPSF) / (n + (float)NEMB * EPSF) * n;
    const int o = d * NEMB + (jh << 8) + tid;
    const float navg = DECAYF * avg_in[o] + OMDF * s;
    out_avg[o] = navg;
    out_w[o] = navg / csj;
    if (blockIdx.x == 0) { out_ncs[tid] = ncs0; out_ncs[tid + 256] = ncs1; }
}

// pure gather result write (unchanged). Runs LAST (out_result overlays es_p).
__global__ __launch_bounds__(512) void result_kernel(
    const float* __restrict__ w, const float* __restrict__ arg,
    float* __restrict__ out_result)
{
    __shared__ float wrow8[8 * 512];
    const int tid = threadIdx.x;
    const int grp = blockIdx.x >> 6;
    const int chunk = blockIdx.x & 63;
#pragma unroll
    for (int d = 0; d < 8; ++d)
        wrow8[(d << 9) + tid] = w[((grp << 3) + d) * NEMB + tid];
    __syncthreads();

    const int t = (chunk << 11) + (tid << 2);
    const int o = (t >> 12) * BSTR + (t & 4095);
    float4 a4 = *(const float4*)(arg + t);
    int j0 = ((int)a4.x) & 511, j1 = ((int)a4.y) & 511;
    int j2 = ((int)a4.z) & 511, j3 = ((int)a4.w) & 511;
#pragma unroll
    for (int d = 0; d < 8; ++d) {
        const int dg = (grp << 3) + d;
        float4 r4 = {wrow8[(d << 9) + j0], wrow8[(d << 9) + j1],
                     wrow8[(d << 9) + j2], wrow8[(d << 9) + j3]};
        *(float4*)(out_result + o + dg * 4096) = r4;
    }
}

extern "C" void kernel_launch(void* const* d_in, const int* in_sizes, int n_in,
                              void* d_out, int out_size, void* d_ws, size_t ws_size,
                              hipStream_t stream) {
    (void)in_sizes; (void)n_in; (void)out_size; (void)ws_size;
    const float* x   = (const float*)d_in[0];
    const float* w   = (const float*)d_in[1];
    const float* cs  = (const float*)d_in[2];
    const float* avg = (const float*)d_in[3];

    float* out = (float*)d_out;
    float* out_result = out;                 // 8388608 floats
    float* out_arg    = out + 8388608;       // 131072
    float* out_w      = out + 8519680;       // 32768
    float* out_ncs    = out + 8552448;       // 512
    float* out_avg    = out + 8552960;       // 32768
    float* es_p       = out;                 // 32MB scratch in out_result region;
                                             // consumed by finalize BEFORE result_kernel

    char* wsb = (char*)d_ws;
    unsigned short* wh = (unsigned short*)wsb;             // 65536 B
    unsigned short* wl = (unsigned short*)(wsb + 65536);   // 65536 B
    float* wsq      = (float*)(wsb + 131072);              // 2048 B
    float* cnt_ws   = (float*)(wsb + 133120);              // 2048 B
    unsigned* gcnt  = (unsigned*)(wsb + 135168);           // 4 B
    int* queue      = (int*)(wsb + 135232);                // 131072 B

    prep_kernel<<<9, 512, 0, stream>>>(w, wh, wl, wsq, cnt_ws, gcnt);
    vq_main<<<1024, 512, 0, stream>>>(x, wh, wl, wsq, out_arg, gcnt, queue);
    refine_kernel<<<256, 256, 0, stream>>>(x, w, wsq, gcnt, queue, out_arg);
    es_kernel<<<512, 512, 0, stream>>>(x, out_arg, es_p, cnt_ws);
    finalize_kernel<<<128, 256, 0, stream>>>(cs, avg, cnt_ws, es_p, out_w, out_ncs, out_avg);
    result_kernel<<<512, 512, 0, stream>>>(w, out_arg, out_result);
}

// Round 11
// 174.426 us; speedup vs baseline: 1.3668x; 1.0231x over previous
//
#include <hip/hip_runtime.h>

#define NEMB 512
#define EMB 64
#define BSTR 262144          // 64*4096
#define DECAYF 0.99f
#define OMDF 0.01f
#define EPSF 1e-5f
#define GAP_T 0.002f         // 3-term split err ~1e-4 realistic -> 20x margin
#define QCAP 32768           // flagged-token queue capacity

typedef __attribute__((ext_vector_type(8))) short bf16x8;
typedef __attribute__((ext_vector_type(4))) float f32x4;

__device__ __forceinline__ unsigned short f2bf(float f) {
    unsigned u = __float_as_uint(f);
    return (unsigned short)((u + 0x7FFFu + ((u >> 16) & 1u)) >> 16);   // RNE
}
__device__ __forceinline__ float bf2f(unsigned short h) {
    return __uint_as_float(((unsigned)h) << 16);
}

// global->LDS DMA, 16B/lane. LDS dest = wave-uniform base + lane*16 (HW rule);
// global src is per-lane (swizzles applied on the SOURCE address).
__device__ __forceinline__ void gl2lds16(const void* g, void* l) {
    __builtin_amdgcn_global_load_lds(
        (const __attribute__((address_space(1))) unsigned int*)g,
        (__attribute__((address_space(3))) unsigned int*)l, 16, 0, 0);
}

// 9 blocks x 512 threads.
__global__ void prep_kernel(const float* __restrict__ w,
                            unsigned short* __restrict__ wh, unsigned short* __restrict__ wl,
                            float* __restrict__ wsq,
                            float* __restrict__ cnt_ws, unsigned* __restrict__ gcnt) {
    int j = threadIdx.x;
    if (blockIdx.x < 8) {
        int d0 = blockIdx.x << 3;
        bf16x8 hb, lb;
#pragma unroll
        for (int i = 0; i < 8; ++i) {
            float v = w[(d0 + i) * NEMB + j];
            unsigned short h = f2bf(v);
            hb[i] = (short)h;
            lb[i] = (short)f2bf(v - bf2f(h));
        }
        *(bf16x8*)(wh + j * EMB + d0) = hb;
        *(bf16x8*)(wl + j * EMB + d0) = lb;
    } else {
        float s = 0.f;
#pragma unroll
        for (int d = 0; d < EMB; ++d) { float v = w[d * NEMB + j]; s = fmaf(v, v, s); }
        wsq[j] = s;
        cnt_ws[j] = 0.f;
        if (j == 0) *gcnt = 0u;
    }
}

#define UPD(S1, J1, S2, J2, s_, j_) do { \
    if (s_ < S1 || (s_ == S1 && j_ < J1)) { S2 = S1; J2 = J1; S1 = s_; J1 = j_; } \
    else if (s_ < S2 || (s_ == S2 && j_ < J2)) { S2 = s_; J2 = j_; } } while (0)

// issue one 64-code slot stage (16KB: hi 8KB + lo 8KB) via gload_lds, no barrier.
// slotk in {0,1}; cbase = first code. Source-side XOR swizzle (LDS stays linear).
#define STAGE_CB(slotk, cbase) do {                                               \
    _Pragma("unroll")                                                             \
    for (int it_ = 0; it_ < 2; ++it_) {                                           \
        int win0_ = (wave << 6);                  /* wave-uniform granule base */ \
        int win_  = win0_ + lane;                                                 \
        int row_  = win_ >> 3, sl_ = win_ & 7;                                    \
        const unsigned short* src_ =                                              \
            (it_ ? wl : wh) + ((cbase) + row_) * EMB + ((sl_ ^ (row_ & 7)) << 3); \
        unsigned short* dst_ = (unsigned short*)ubuf + (slotk) * 8192             \
                               + it_ * 4096 + (win0_ << 3);                       \
        gl2lds16(src_, dst_);                                                     \
    }                                                                             \
} while (0)

// r11: 1024 blocks x 512 thr x 128 tokens. Changes vs r10 (vq only):
// (1) 3-term split restored (6 MFMA/iter; r9's 4th term was +33% MFMA for accuracy
//     the refine path already covers — r0/r5 passed 3-term at GAP_T .012/.006).
// (2) GAP_T = 0.002 (20x over realistic 3-term err ~1e-4; inside r5's validated .006).
// (3) codebook double-buffered in TWO 16KB 64-code slots inside the same 32KB union:
//     stage slot s+1 ISSUED BEFORE computing slot s, ONE barrier per stage ->
//     staging latency hides under compute (r10 exposed it between two barriers 4x).
// LDS stays 34.8KB -> 4 blocks/CU capable; bounds (512,4): natural VGPR ~48-64.
__global__ __launch_bounds__(512, 4) void vq_main(
    const float* __restrict__ x,
    const unsigned short* __restrict__ wh, const unsigned short* __restrict__ wl,
    const float* __restrict__ wsq,
    float* __restrict__ out_arg, unsigned* __restrict__ gcnt, int* __restrict__ queue)
{
    __shared__ __align__(16) unsigned char ubuf[32768];   // x tile | 2 cb slots
    __shared__ float wsq_s[NEMB];

    float* xt = (float*)ubuf;                        // [64][128] f32 = 32KB

    const int tid = threadIdx.x;
    const int blk = blockIdx.x;          // 1024
    const int b    = blk >> 5;
    const int hgrp = blk & 31;
    const int t0 = b * 4096 + hgrp * 128;
    const float* xbase = x + b * BSTR + hgrp * 128;

    const int lane = tid & 63;
    const int wave = tid >> 6;

    // ---- stage x tile: 32 chunks of 1KB (2 rows of 128 f32 each) ----
#pragma unroll
    for (int it = 0; it < 4; ++it) {
        int ch = wave + (it << 3);
        int d0 = ch << 1;
        gl2lds16(xbase + (d0 + (lane >> 5)) * 4096 + ((lane & 31) << 2),
                 xt + d0 * 128);
    }
    wsq_s[tid] = wsq[tid];
    __syncthreads();                     // xt + wsq ready

    const int l15  = lane & 15;
    const int quad = lane >> 4;
    const int wbase = wave << 4;         // 16 tokens per wave

    // ---- A fragments (hi/lo split) + fused ||x||^2 ----
    bf16x8 ah[2], al[2];
    float xq[4];
    {
        int m = wbase + l15;
        float sq = 0.f;
#pragma unroll
        for (int ks = 0; ks < 2; ++ks) {
            int k0 = (ks << 5) + (quad << 3);
            bf16x8 hh, ll;
#pragma unroll
            for (int i = 0; i < 8; ++i) {
                float v = xt[(k0 + i) * 128 + m];
                sq = fmaf(v, v, sq);
                unsigned short h = f2bf(v);
                hh[i] = (short)h;
                ll[i] = (short)f2bf(v - bf2f(h));
            }
            ah[ks] = hh; al[ks] = ll;
        }
        sq += __shfl_xor(sq, 16, 64);    // quads hold disjoint 16-dim partials
        sq += __shfl_xor(sq, 32, 64);
#pragma unroll
        for (int r = 0; r < 4; ++r)
            xq[r] = __shfl(sq, (quad << 2) + r, 64);
    }
    __syncthreads();                     // xt dead; ubuf free for codebook

    float v1[4], v2[4];
    int   j1[4];
#pragma unroll
    for (int r = 0; r < 4; ++r) { v1[r] = 3.4e38f; v2[r] = 3.4e38f; j1[r] = 0; }

    const int m7 = l15 & 7;
    const int s0off = ((quad ^ m7) << 3);
    const int s1off = (((4 | quad) ^ m7) << 3);

    STAGE_CB(0, 0);                      // slot 0 <- codes 0..63
    __syncthreads();                     // slot 0 ready

    for (int s = 0; s < 8; ++s) {
        const int k = s & 1;
        if (s < 7) STAGE_CB(k ^ 1, (s + 1) << 6);    // overlaps with compute below
        const unsigned short* whs_k = (const unsigned short*)ubuf + k * 8192;
        const unsigned short* wls_k = whs_k + 4096;
        const int nbase = s << 6;
#pragma unroll
        for (int it = 0; it < 4; ++it) {
            const int ib = ((it << 4) + l15) << 6;    // row*64 shorts, row 0..63
            bf16x8 b0 = *(const bf16x8*)(whs_k + ib + s0off);
            bf16x8 b1 = *(const bf16x8*)(whs_k + ib + s1off);
            bf16x8 b2 = *(const bf16x8*)(wls_k + ib + s0off);
            bf16x8 b3 = *(const bf16x8*)(wls_k + ib + s1off);
            const int n = nbase + (it << 4) + l15;
            float wq = wsq_s[n];

            // 3-term split: hi*hi + hi*lo + lo*hi (6 MFMA)
            f32x4 acc = (f32x4){0.f, 0.f, 0.f, 0.f};
            acc = __builtin_amdgcn_mfma_f32_16x16x32_bf16(ah[0], b0, acc, 0, 0, 0);
            acc = __builtin_amdgcn_mfma_f32_16x16x32_bf16(ah[1], b1, acc, 0, 0, 0);
            acc = __builtin_amdgcn_mfma_f32_16x16x32_bf16(ah[0], b2, acc, 0, 0, 0);
            acc = __builtin_amdgcn_mfma_f32_16x16x32_bf16(ah[1], b3, acc, 0, 0, 0);
            acc = __builtin_amdgcn_mfma_f32_16x16x32_bf16(al[0], b0, acc, 0, 0, 0);
            acc = __builtin_amdgcn_mfma_f32_16x16x32_bf16(al[1], b1, acc, 0, 0, 0);

#pragma unroll
            for (int r = 0; r < 4; ++r) {
                float s0 = fmaf(-2.f, acc[r], xq[r] + wq);
                bool p0 = s0 < v1[r];
                float mx0 = fmaxf(s0, v1[r]);
                v1[r] = fminf(s0, v1[r]);
                v2[r] = fminf(v2[r], mx0);
                j1[r] = p0 ? n : j1[r];
            }
        }
        __syncthreads();   // slot s+1 staged AND slot s fully read
    }

    // butterfly merge (v1,j1,v2) across the 16 lanes sharing each token
#pragma unroll
    for (int r = 0; r < 4; ++r) {
        float a1 = v1[r], a2 = v2[r];
        int   aj = j1[r];
#pragma unroll
        for (int msk = 1; msk < 16; msk <<= 1) {
            float o1 = __shfl_xor(a1, msk, 64);
            int   oj = __shfl_xor(aj, msk, 64);
            float o2 = __shfl_xor(a2, msk, 64);
            bool take = (o1 < a1) || (o1 == a1 && oj < aj);
            float mx = fmaxf(a1, o1);
            a2 = fminf(fminf(a2, o2), mx);
            a1 = fminf(a1, o1);
            aj = take ? oj : aj;
        }
        v1[r] = a1; v2[r] = a2; j1[r] = aj;
    }

    if (l15 == 0) {
#pragma unroll
        for (int r = 0; r < 4; ++r) {
            int gt = t0 + wbase + (quad << 2) + r;
            out_arg[gt] = (float)j1[r];
            if (v2[r] - v1[r] < GAP_T) {
                unsigned idx = atomicAdd(gcnt, 1u);
                if (idx < QCAP) queue[idx] = gt;
            }
        }
    }
}

// Globally balanced exact refine (unchanged).
__global__ __launch_bounds__(256) void refine_kernel(
    const float* __restrict__ x, const float* __restrict__ w,
    const float* __restrict__ wsq, const unsigned* __restrict__ gcnt,
    const int* __restrict__ queue, float* __restrict__ out_arg)
{
    __shared__ float wsq_s[NEMB];
    const int tid = threadIdx.x;
    wsq_s[tid] = wsq[tid];
    wsq_s[tid + 256] = wsq[tid + 256];
    __syncthreads();

    unsigned nfu = *gcnt;
    const int nf = (int)(nfu < (unsigned)QCAP ? nfu : (unsigned)QCAP);
    const int lane = tid & 63;
    const int gw = (blockIdx.x << 2) + (tid >> 6);

    for (int i = gw; i < nf; i += 1024) {
        const int t = queue[i] & 131071;
        const int b = t >> 12, pos = t & 4095;
        float xd = x[b * BSTR + lane * 4096 + pos];
        float xqv = xd * xd;
#pragma unroll
        for (int mk = 1; mk < 64; mk <<= 1) xqv += __shfl_xor(xqv, mk, 64);

        float accv[8];
#pragma unroll
        for (int k = 0; k < 8; ++k) accv[k] = 0.f;
#pragma unroll 4
        for (int d = 0; d < EMB; ++d) {
            float4 wa = *(const float4*)(w + d * NEMB + (lane << 2));
            float4 wb = *(const float4*)(w + d * NEMB + 256 + (lane << 2));
            float xv = __shfl(xd, d, 64);
            accv[0] = fmaf(xv, wa.x, accv[0]);
            accv[1] = fmaf(xv, wa.y, accv[1]);
            accv[2] = fmaf(xv, wa.z, accv[2]);
            accv[3] = fmaf(xv, wa.w, accv[3]);
            accv[4] = fmaf(xv, wb.x, accv[4]);
            accv[5] = fmaf(xv, wb.y, accv[5]);
            accv[6] = fmaf(xv, wb.z, accv[6]);
            accv[7] = fmaf(xv, wb.w, accv[7]);
        }

        float S1 = 3.4e38f, S2 = 3.4e38f; int J1 = 0, J2 = 0;
#pragma unroll
        for (int k = 0; k < 8; ++k) {
            int j = (k < 4) ? ((lane << 2) + k) : (256 + (lane << 2) + k - 4);
            float s = (xqv - 2.f * accv[k]) + wsq_s[j];
            UPD(S1, J1, S2, J2, s, j);
        }
#pragma unroll
        for (int mk = 1; mk < 64; mk <<= 1) {
            float os1 = __shfl_xor(S1, mk, 64); int oj1 = __shfl_xor(J1, mk, 64);
            float os2 = __shfl_xor(S2, mk, 64); int oj2 = __shfl_xor(J2, mk, 64);
            UPD(S1, J1, S2, J2, os1, oj1);
            UPD(S1, J1, S2, J2, os2, oj2);
        }

        int jm = J1;
        if (S2 - S1 < 1e-3f) {
            float w1 = w[lane * NEMB + J1];
            float w2 = w[lane * NEMB + J2];
            double e1 = (double)w1 * (double)w1 - 2.0 * (double)xd * (double)w1;
            double e2 = (double)w2 * (double)w2 - 2.0 * (double)xd * (double)w2;
#pragma unroll
            for (int mk = 1; mk < 64; mk <<= 1) {
                e1 += __shfl_xor(e1, mk, 64);
                e2 += __shfl_xor(e2, mk, 64);
            }
            if (e2 < e1 || (e2 == e1 && J2 < J1)) jm = J2;
        }
        if (lane == 0) out_arg[t] = (float)jm;
    }
}

// es GEMM (r6-verified, unchanged): 512 blocks, 512 tokens/block, bf16-HI only.
__global__ __launch_bounds__(512, 4) void es_kernel(
    const float* __restrict__ x, const float* __restrict__ arg,
    float* __restrict__ es_p, float* __restrict__ cnt_ws)
{
    __shared__ unsigned short xh[16384];   // [64][256] bf16-hi, swizzled
    __shared__ int args_s[256];
    __shared__ float cacc[NEMB];

    const int tid = threadIdx.x;
    const int blk = blockIdx.x;          // 512
    const int flavor = blk & 1;          // j range [flavor*256, +256)
    const int chunk  = blk >> 1;         // 0..255, 512 tokens
    const int b = chunk >> 3;
    const int tpos0 = (chunk & 7) << 9;

    cacc[tid] = 0.f;

    const int lane = tid & 63;
    const int wave = tid >> 6;
    const int l15  = lane & 15;
    const int quad = lane >> 4;
    const int jb   = wave << 5;

    f32x4 acc[4][2];
#pragma unroll
    for (int m = 0; m < 4; ++m)
#pragma unroll
        for (int nc = 0; nc < 2; ++nc) acc[m][nc] = (f32x4){0.f, 0.f, 0.f, 0.f};

    for (int st = 0; st < 2; ++st) {
        const int tpos = tpos0 + (st << 8);
#pragma unroll
        for (int it = 0; it < 8; ++it) {
            int idx = tid + (it << 9);
            int d = idx >> 6, q = idx & 63;
            float4 g = *(const float4*)(x + b * BSTR + d * 4096 + tpos + (q << 2));
            int c = q >> 1, half = q & 1;
            int off = d * 256 + ((c ^ (d & 7)) << 3) + (half << 2);
            ushort4 hv = {f2bf(g.x), f2bf(g.y), f2bf(g.z), f2bf(g.w)};
            *(ushort4*)(xh + off) = hv;
        }
        if (tid < 256) args_s[tid] = ((int)arg[b * 4096 + tpos + tid]) & 511;
        __syncthreads();

        if (flavor == 0 && tid < 256) atomicAdd(&cacc[args_s[tid]], 1.f);

#pragma unroll
        for (int kk = 0; kk < 8; ++kk) {
            bf16x8 a_[4];
#pragma unroll
            for (int m = 0; m < 4; ++m) {
                int d = (m << 4) + l15;
                int coff = ((((kk << 2) + quad) ^ (d & 7)) << 3);
                a_[m] = *(const bf16x8*)(xh + d * 256 + coff);
            }
            int argv[8];
            const int kb = (kk << 5) + (quad << 3);
#pragma unroll
            for (int i = 0; i < 8; ++i) argv[i] = args_s[kb + i];
#pragma unroll
            for (int nc = 0; nc < 2; ++nc) {
                const int jg = (flavor << 8) + jb + (nc << 4) + l15;   // GLOBAL code id
                bf16x8 bf;
#pragma unroll
                for (int i = 0; i < 8; ++i) bf[i] = (argv[i] == jg) ? (short)0x3F80 : (short)0;
#pragma unroll
                for (int m = 0; m < 4; ++m)
                    acc[m][nc] = __builtin_amdgcn_mfma_f32_16x16x32_bf16(a_[m], bf, acc[m][nc], 0, 0, 0);
            }
        }
        __syncthreads();
    }

    // ---- flush deterministic partial: es_p[blk][d][jl] ----
    float* ep = es_p + blk * 16384;
#pragma unroll
    for (int m = 0; m < 4; ++m)
#pragma unroll
        for (int nc = 0; nc < 2; ++nc) {
            const int jl = jb + (nc << 4) + l15;
#pragma unroll
            for (int r = 0; r < 4; ++r) {
                const int d = (m << 4) + (quad << 2) + r;
                ep[d * 256 + jl] = acc[m][nc][r];
            }
        }
    if (flavor == 0) {
        float v = cacc[tid];
        if (v != 0.f) atomicAdd(&cnt_ws[tid], v);
    }
}

// fused finalize + es partial reduction: 128 blocks (64 d x 2 j-halves) x 256 thr.
__global__ __launch_bounds__(256) void finalize_kernel(
    const float* __restrict__ cs_in, const float* __restrict__ avg_in,
    const float* __restrict__ cnt_ws, const float* __restrict__ es_p,
    float* __restrict__ out_w, float* __restrict__ out_ncs,
    float* __restrict__ out_avg) {
    __shared__ float red[256];
    const int tid = threadIdx.x;
    const int d  = blockIdx.x >> 1;
    const int jh = blockIdx.x & 1;

    float c0 = cnt_ws[tid], c1 = cnt_ws[tid + 256];
    float ncs0 = DECAYF * cs_in[tid] + OMDF * ((c0 == 0.f) ? 1.f : c0);
    float ncs1 = DECAYF * cs_in[tid + 256] + OMDF * ((c1 == 0.f) ? 1.f : c1);
    red[tid] = ncs0 + ncs1;
    __syncthreads();
    for (int s = 128; s > 0; s >>= 1) {
        if (tid < s) red[tid] += red[tid + s];
        __syncthreads();
    }
    const float n = red[0];

    const float* ep = es_p + jh * 16384 + d * 256 + tid;
    float s = 0.f;
#pragma unroll 16
    for (int c = 0; c < 256; ++c) s += ep[c * 32768];

    const float ncs = jh ? ncs1 : ncs0;
    const float csj = (ncs + EPSF) / (n + (float)NEMB * EPSF) * n;
    const int o = d * NEMB + (jh << 8) + tid;
    const float navg = DECAYF * avg_in[o] + OMDF * s;
    out_avg[o] = navg;
    out_w[o] = navg / csj;
    if (blockIdx.x == 0) { out_ncs[tid] = ncs0; out_ncs[tid + 256] = ncs1; }
}

// pure gather result write (unchanged). Runs LAST (out_result overlays es_p).
__global__ __launch_bounds__(512) void result_kernel(
    const float* __restrict__ w, const float* __restrict__ arg,
    float* __restrict__ out_result)
{
    __shared__ float wrow8[8 * 512];
    const int tid = threadIdx.x;
    const int grp = blockIdx.x >> 6;
    const int chunk = blockIdx.x & 63;
#pragma unroll
    for (int d = 0; d < 8; ++d)
        wrow8[(d << 9) + tid] = w[((grp << 3) + d) * NEMB + tid];
    __syncthreads();

    const int t = (chunk << 11) + (tid << 2);
    const int o = (t >> 12) * BSTR + (t & 4095);
    float4 a4 = *(const float4*)(arg + t);
    int j0 = ((int)a4.x) & 511, j1 = ((int)a4.y) & 511;
    int j2 = ((int)a4.z) & 511, j3 = ((int)a4.w) & 511;
#pragma unroll
    for (int d = 0; d < 8; ++d) {
        const int dg = (grp << 3) + d;
        float4 r4 = {wrow8[(d << 9) + j0], wrow8[(d << 9) + j1],
                     wrow8[(d << 9) + j2], wrow8[(d << 9) + j3]};
        *(float4*)(out_result + o + dg * 4096) = r4;
    }
}

extern "C" void kernel_launch(void* const* d_in, const int* in_sizes, int n_in,
                              void* d_out, int out_size, void* d_ws, size_t ws_size,
                              hipStream_t stream) {
    (void)in_sizes; (void)n_in; (void)out_size; (void)ws_size;
    const float* x   = (const float*)d_in[0];
    const float* w   = (const float*)d_in[1];
    const float* cs  = (const float*)d_in[2];
    const float* avg = (const float*)d_in[3];

    float* out = (float*)d_out;
    float* out_result = out;                 // 8388608 floats
    float* out_arg    = out + 8388608;       // 131072
    float* out_w      = out + 8519680;       // 32768
    float* out_ncs    = out + 8552448;       // 512
    float* out_avg    = out + 8552960;       // 32768
    float* es_p       = out;                 // 32MB scratch in out_result region;
                                             // consumed by finalize BEFORE result_kernel

    char* wsb = (char*)d_ws;
    unsigned short* wh = (unsigned short*)wsb;             // 65536 B
    unsigned short* wl = (unsigned short*)(wsb + 65536);   // 65536 B
    float* wsq      = (float*)(wsb + 131072);              // 2048 B
    float* cnt_ws   = (float*)(wsb + 133120);              // 2048 B
    unsigned* gcnt  = (unsigned*)(wsb + 135168);           // 4 B
    int* queue      = (int*)(wsb + 135232);                // 131072 B

    prep_kernel<<<9, 512, 0, stream>>>(w, wh, wl, wsq, cnt_ws, gcnt);
    vq_main<<<1024, 512, 0, stream>>>(x, wh, wl, wsq, out_arg, gcnt, queue);
    refine_kernel<<<256, 256, 0, stream>>>(x, w, wsq, gcnt, queue, out_arg);
    es_kernel<<<512, 512, 0, stream>>>(x, out_arg, es_p, cnt_ws);
    finalize_kernel<<<128, 256, 0, stream>>>(cs, avg, cnt_ws, es_p, out_w, out_ncs, out_avg);
    result_kernel<<<512, 512, 0, stream>>>(w, out_arg, out_result);
}